// Round 1
// baseline (114.843 us; speedup 1.0000x reference)
//
#include <hip/hip_runtime.h>
#include <hip/hip_bf16.h>

#define NUM_GT 25
#define NUM_PRED 40
#define NGT1 (NUM_GT + 1)       // 26
#define NPRED1 (NUM_PRED + 1)   // 41
#define NBINS (NPRED1 * NGT1)   // 1066
#define SMOOTH 1.0

// ---------------------------------------------------------------------------
// Kernel 1: joint histogram counts[p][c] = #voxels with round(pred)==p, gt==c
// Per-wave LDS sub-histograms (4 waves / 256-thread block) to reduce LDS
// atomic contention; one global atomicAdd pass per block at the end.
// ---------------------------------------------------------------------------
__global__ __launch_bounds__(256) void hist_kernel(
    const float* __restrict__ pred, const int* __restrict__ gt,
    unsigned int* __restrict__ hist, int n)
{
    __shared__ unsigned int sh[4 * NBINS];
    const int tid = threadIdx.x;
    const int wave = tid >> 6;
    unsigned int* h = &sh[wave * NBINS];

    for (int i = tid; i < 4 * NBINS; i += blockDim.x) sh[i] = 0u;
    __syncthreads();

    const int gtid = blockIdx.x * blockDim.x + tid;
    const int stride = gridDim.x * blockDim.x;

    const int n4 = n >> 2;  // n = 256^3, divisible by 4
    const float4* __restrict__ p4 = (const float4*)pred;
    const int4* __restrict__ g4 = (const int4*)gt;

    for (int i = gtid; i < n4; i += stride) {
        float4 p = p4[i];
        int4 g = g4[i];
        int l0 = __float2int_rn(p.x);
        int l1 = __float2int_rn(p.y);
        int l2 = __float2int_rn(p.z);
        int l3 = __float2int_rn(p.w);
        atomicAdd(&h[l0 * NGT1 + g.x], 1u);
        atomicAdd(&h[l1 * NGT1 + g.y], 1u);
        atomicAdd(&h[l2 * NGT1 + g.z], 1u);
        atomicAdd(&h[l3 * NGT1 + g.w], 1u);
    }
    // tail (defensive; n divisible by 4 here)
    for (int i = (n4 << 2) + gtid; i < n; i += stride) {
        int l = __float2int_rn(pred[i]);
        atomicAdd(&h[l * NGT1 + gt[i]], 1u);
    }

    __syncthreads();
    for (int i = tid; i < NBINS; i += blockDim.x) {
        unsigned int s = sh[i] + sh[NBINS + i] + sh[2 * NBINS + i] + sh[3 * NBINS + i];
        if (s) atomicAdd(&hist[i], s);
    }
}

// ---------------------------------------------------------------------------
// Kernel 2: O(1066) finisher. Cooperative LDS load, then lane 0 computes the
// scalar in double precision (counts are exact integers; fp64 removes any
// accumulation-order concern vs the numpy reference).
// ---------------------------------------------------------------------------
__global__ __launch_bounds__(64) void finish_kernel(
    const unsigned int* __restrict__ hist, float* __restrict__ out)
{
    __shared__ unsigned int h[NBINS];
    for (int i = threadIdx.x; i < NBINS; i += 64) h[i] = hist[i];
    __syncthreads();

    if (threadIdx.x == 0) {
        double pred_sizes[NPRED1];
        // pred_sizes[p] = sum_c counts[p][c]
        for (int p = 0; p < NPRED1; ++p) {
            double s = 0.0;
            for (int c = 0; c < NGT1; ++c) s += (double)h[p * NGT1 + c];
            pred_sizes[p] = s;
        }

        double lesion_dice = 0.0;
        int num_gt = 0;
        bool present[NUM_GT];
        for (int c = 0; c < NUM_GT; ++c) {      // gt label = c+1
            double gt_size = 0.0;
            double union_size = 0.0;
            for (int p = 0; p < NPRED1; ++p) {
                unsigned int cnt = h[p * NGT1 + (c + 1)];
                gt_size += (double)cnt;
                if (cnt > 0) union_size += pred_sizes[p];
            }
            bool pres = gt_size > 0.0;
            present[c] = pres;
            if (pres) {
                num_gt += 1;
                lesion_dice += 2.0 * gt_size / (union_size + gt_size + SMOOTH);
            }
        }

        int fp = 0;
        for (int p = 0; p < NPRED1; ++p) {
            if (pred_sizes[p] > 0.0) {
                bool tp_any = false;
                for (int c = 0; c < NUM_GT; ++c) {
                    if (present[c] && h[p * NGT1 + (c + 1)] > 0) { tp_any = true; break; }
                }
                if (!tp_any) fp += 1;
            }
        }

        out[0] = (float)(lesion_dice / (double)(num_gt + fp));
    }
}

extern "C" void kernel_launch(void* const* d_in, const int* in_sizes, int n_in,
                              void* d_out, int out_size, void* d_ws, size_t ws_size,
                              hipStream_t stream) {
    const float* pred = (const float*)d_in[0];
    const int* gt = (const int*)d_in[1];
    float* out = (float*)d_out;
    unsigned int* hist = (unsigned int*)d_ws;
    const int n = in_sizes[0];

    hipMemsetAsync(hist, 0, NBINS * sizeof(unsigned int), stream);

    const int block = 256;
    const int grid = 2048;  // 16.7M voxels / (2048*256 lanes * 4/lane) = 8 iters
    hist_kernel<<<grid, block, 0, stream>>>(pred, gt, hist, n);
    finish_kernel<<<1, 64, 0, stream>>>(hist, out);
}